// Round 1
// 1524.372 us; speedup vs baseline: 1.3091x; 1.3091x over previous
//
#include <hip/hip_runtime.h>
#include <math.h>

// R2: move both edge GEMMs (K-proj+score, V-proj) onto bf16 MFMA in ONE fused
// kernel. edge_attr tile staged to LDS once (bf16, XOR-swizzled), W_K|W_V held
// as register B-fragments (prebuilt bf16 n-major). Scores/phi/V written at CSR
// slots -> stats/gather are contiguous streams, elist eliminated.
#define NN 50000
#define NE 800000
#define D  128
#define NH 8

typedef __attribute__((ext_vector_type(8))) short bf16x8;
typedef __attribute__((ext_vector_type(4))) float f32x4;

__device__ __forceinline__ unsigned short f2bf(float f) {  // RNE
  unsigned x = __float_as_uint(f);
  unsigned r = ((x >> 16) & 1u) + 0x7FFFu;
  return (unsigned short)((x + r) >> 16);
}

// ---------- f32 VALU GEMM (kept for Q and O projections, N=50000) ----------
__device__ __forceinline__ void load_tile(const float* __restrict__ A, int row0, int M,
                                          float (*As)[65], int tid) {
#pragma unroll
  for (int i = 0; i < 8; ++i) {
    int p = tid + i * 256;
    int r = p >> 5;
    int c = (p & 31) << 2;
    float4 v = make_float4(0.f, 0.f, 0.f, 0.f);
    int row = row0 + r;
    if (row < M) v = *(const float4*)(A + (size_t)row * D + c);
    As[c + 0][r] = v.x;
    As[c + 1][r] = v.y;
    As[c + 2][r] = v.z;
    As[c + 3][r] = v.w;
  }
}

__device__ __forceinline__ void gemm_core(const float (*As)[65], const float* __restrict__ B,
                                          int ty, int tx, float acc[4][8]) {
#pragma unroll 8
  for (int k = 0; k < 128; ++k) {
    float a[4];
#pragma unroll
    for (int r = 0; r < 4; ++r) a[r] = As[k][ty * 4 + r];
    float4 b0 = *(const float4*)(B + k * D + tx * 8);
    float4 b1 = *(const float4*)(B + k * D + tx * 8 + 4);
    float b[8] = {b0.x, b0.y, b0.z, b0.w, b1.x, b1.y, b1.z, b1.w};
#pragma unroll
    for (int r = 0; r < 4; ++r)
#pragma unroll
      for (int c = 0; c < 8; ++c) acc[r][c] += a[r] * b[c];
  }
}

__global__ __launch_bounds__(256, 4) void gemm_bias_k(const float* __restrict__ A,
    const float* __restrict__ B, const float* __restrict__ bias,
    float* __restrict__ C, int M) {
  __shared__ float As[128][65];
  int tid = threadIdx.x;
  int row0 = blockIdx.x * 64;
  load_tile(A, row0, M, As, tid);
  __syncthreads();
  int ty = tid >> 4, tx = tid & 15;
  float acc[4][8] = {};
  gemm_core(As, B, ty, tx, acc);
  float4 ba = *(const float4*)(bias + tx * 8);
  float4 bb = *(const float4*)(bias + tx * 8 + 4);
#pragma unroll
  for (int r = 0; r < 4; ++r) {
    int row = row0 + ty * 4 + r;
    if (row < M) {
      float4 o0 = make_float4(acc[r][0] + ba.x, acc[r][1] + ba.y,
                              acc[r][2] + ba.z, acc[r][3] + ba.w);
      float4 o1 = make_float4(acc[r][4] + bb.x, acc[r][5] + bb.y,
                              acc[r][6] + bb.z, acc[r][7] + bb.w);
      *(float4*)(C + (size_t)row * D + tx * 8) = o0;
      *(float4*)(C + (size_t)row * D + tx * 8 + 4) = o1;
    }
  }
}

// ---------- CSR build ----------
__global__ __launch_bounds__(256) void hist_k(const int* __restrict__ jidx,
                                              int* __restrict__ cnt) {
  int e = blockIdx.x * 256 + threadIdx.x;
  atomicAdd(&cnt[jidx[e]], 1);
}

__global__ __launch_bounds__(1024) void scan_k(const int* __restrict__ cnt,
    int* __restrict__ offs, int* __restrict__ cursor) {
  __shared__ int part[1024];
  const int CH = 49;  // 49*1024 >= NN
  int t = threadIdx.x;
  int base = t * CH;
  int s = 0;
  for (int i = 0; i < CH; ++i) {
    int idx = base + i;
    if (idx < NN) s += cnt[idx];
  }
  part[t] = s;
  __syncthreads();
  for (int off = 1; off < 1024; off <<= 1) {
    int v = (t >= off) ? part[t - off] : 0;
    __syncthreads();
    part[t] += v;
    __syncthreads();
  }
  int run = (t == 0) ? 0 : part[t - 1];
  for (int i = 0; i < CH; ++i) {
    int idx = base + i;
    if (idx < NN) {
      offs[idx] = run;
      cursor[idx] = run;
      run += cnt[idx];
    }
  }
  if (t == 1023) offs[NN] = run;
}

__global__ __launch_bounds__(256) void scatter_k(const int* __restrict__ jidx,
    int* __restrict__ cursor, int* __restrict__ pos) {
  int e = blockIdx.x * 256 + threadIdx.x;
  pos[e] = atomicAdd(&cursor[jidx[e]], 1);
}

// ---------- weight prep: WKVT[n][k] = bf16([W_K | W_V][k][n]), n-major ----------
__global__ __launch_bounds__(128) void wprep_k(const float* __restrict__ WK,
    const float* __restrict__ WV, unsigned short* __restrict__ WKVT) {
  int n = blockIdx.x;   // 0..255
  int k = threadIdx.x;  // 0..127
  const float* src = (n < 128) ? WK : WV;
  WKVT[n * 128 + k] = f2bf(src[(size_t)k * 128 + (n & 127)]);
}

// ---------- fused K+V MFMA over edges ----------
// 64 edges x 256 outputs (128 K-cols + 128 V-cols) per block. 4 waves, each
// owns a 64x64 sub-tile. Waves 0,1: K -> per-head Q-dot -> scores (CSR).
// Waves 2,3: V -> bf16 rows at CSR slots (via swizzled LDS assembly).
__global__ __launch_bounds__(256, 2) void kv_mfma_k(
    const float* __restrict__ EA, const unsigned short* __restrict__ WKVT,
    const float* __restrict__ bK, const float* __restrict__ bV,
    const float* __restrict__ Q, const int* __restrict__ jidx,
    const float* __restrict__ elen, const int* __restrict__ pos,
    float* __restrict__ scores_csr, float* __restrict__ phi_csr,
    unsigned short* __restrict__ Vc) {
  __shared__ unsigned short As[64 * 128];  // bf16 A tile, XOR-swizzled, 16KB
  __shared__ unsigned short Vt[64 * 128];  // bf16 V assembly, swizzled, 16KB
  __shared__ float St[64][8];              // scores staging
  int tid = threadIdx.x;
  int e0 = blockIdx.x * 64;

  // stage A: f32 -> bf16, swizzle byte ^= ((row&7)<<4) (ushort: ^((row&7)<<3))
#pragma unroll
  for (int i = 0; i < 4; ++i) {
    int p = tid + i * 256;
    int r = p >> 4;  // row 0..63
    int c = p & 15;  // 8-col chunk
    const float* src = EA + (size_t)(e0 + r) * D + c * 8;
    float4 v0 = *(const float4*)src;
    float4 v1 = *(const float4*)(src + 4);
    unsigned q0 = f2bf(v0.x) | ((unsigned)f2bf(v0.y) << 16);
    unsigned q1 = f2bf(v0.z) | ((unsigned)f2bf(v0.w) << 16);
    unsigned q2 = f2bf(v1.x) | ((unsigned)f2bf(v1.y) << 16);
    unsigned q3 = f2bf(v1.z) | ((unsigned)f2bf(v1.w) << 16);
    int x = (c * 8) ^ ((r & 7) << 3);
    *(uint4*)(As + r * 128 + x) = make_uint4(q0, q1, q2, q3);
  }

  int w = tid >> 6, l = tid & 63;
  int lr = l & 15, lg = l >> 4;

  // B fragments from n-major WKVT: lane lr = col, lg*8 = k-chunk (16B loads)
  bf16x8 Bf[4][4];
  {
    const unsigned short* wb = WKVT + (size_t)(w * 64 + lr) * 128 + lg * 8;
#pragma unroll
    for (int ni = 0; ni < 4; ++ni)
#pragma unroll
      for (int ks = 0; ks < 4; ++ks)
        Bf[ni][ks] = *(const bf16x8*)(wb + ni * 16 * 128 + ks * 32);
  }

  f32x4 acc[4][4] = {};
  __syncthreads();

#pragma unroll
  for (int ks = 0; ks < 4; ++ks)
#pragma unroll
    for (int mi = 0; mi < 4; ++mi) {
      int row = mi * 16 + lr;
      int ku = ks * 32 + lg * 8;
      bf16x8 a = *(const bf16x8*)(As + row * 128 + (ku ^ ((row & 7) << 3)));
#pragma unroll
      for (int ni = 0; ni < 4; ++ni)
        acc[mi][ni] = __builtin_amdgcn_mfma_f32_16x16x32_bf16(a, Bf[ni][ks],
                                                              acc[mi][ni], 0, 0, 0);
    }

  // C layout (m89-verified): col = lane&15, row = (lane>>4)*4 + reg
  if (w < 2) {  // K waves -> scores
    float bk[4];
#pragma unroll
    for (int ni = 0; ni < 4; ++ni) bk[ni] = bK[w * 64 + ni * 16 + lr];
#pragma unroll
    for (int mi = 0; mi < 4; ++mi)
#pragma unroll
      for (int r = 0; r < 4; ++r) {
        int erow = mi * 16 + lg * 4 + r;
        int e = e0 + erow;
        int jn = jidx[e];
        const float* qrow = Q + (size_t)jn * D + w * 64;
#pragma unroll
        for (int ni = 0; ni < 4; ++ni) {  // head h = w*4 + ni
          float t = (acc[mi][ni][r] + bk[ni]) * qrow[ni * 16 + lr];
          t += __shfl_xor(t, 1);
          t += __shfl_xor(t, 2);
          t += __shfl_xor(t, 4);
          t += __shfl_xor(t, 8);
          if (lr == 0) St[erow][w * 4 + ni] = t * 0.25f;
        }
        if (w == 0 && lr == 0) {
          float ln = elen[e];
          phi_csr[pos[e]] = 0.5f * (cosf(ln * 0.628318530717958647f) + 1.0f);
        }
      }
  } else {  // V waves -> swizzled LDS assembly
    float bv[4];
#pragma unroll
    for (int ni = 0; ni < 4; ++ni) bv[ni] = bV[(w - 2) * 64 + ni * 16 + lr];
#pragma unroll
    for (int mi = 0; mi < 4; ++mi)
#pragma unroll
      for (int r = 0; r < 4; ++r) {
        int row = mi * 16 + lg * 4 + r;
        int sw = ((row >> 2) & 7) << 4;
#pragma unroll
        for (int ni = 0; ni < 4; ++ni) {
          int vcol = (w - 2) * 64 + ni * 16 + lr;
          Vt[row * 128 + (vcol ^ sw)] = f2bf(acc[mi][ni][r] + bv[ni]);
        }
      }
  }
  __syncthreads();

  // scores out: 64 rows x 32B, CSR slots
  if (tid < 128) {
    int row = tid >> 1;
    int half = tid & 1;
    int pp = pos[e0 + row];
    float4 s = *(const float4*)(&St[row][half * 4]);
    *(float4*)(scores_csr + (size_t)pp * NH + half * 4) = s;
  }
  // V out: 64 rows x 256B, CSR slots, coalesced 16B chunks
#pragma unroll
  for (int i = 0; i < 4; ++i) {
    int p = tid + i * 256;
    int row = p >> 4, c = p & 15;
    int pp = pos[e0 + row];
    int x0 = (c * 8) ^ (((row >> 2) & 7) << 4);
    uint4 v = *(const uint4*)(Vt + row * 128 + x0);
    *(uint4*)(Vc + (size_t)pp * D + c * 8) = v;
  }
}

// ---------- per-node softmax stats over contiguous CSR scores ----------
__global__ __launch_bounds__(256) void stats2_k(const float* __restrict__ scores_csr,
    const int* __restrict__ offs, float* __restrict__ m, float* __restrict__ den) {
  int tid = threadIdx.x;
  int n = blockIdx.x * 4 + (tid >> 6);
  int l = tid & 63;
  int h = l & 7;
  int o0 = offs[n], o1 = offs[n + 1];
  float mx = -INFINITY;
  for (int i = o0 + (l >> 3); i < o1; i += 8)
    mx = fmaxf(mx, scores_csr[(size_t)i * NH + h]);
#pragma unroll
  for (int d = 8; d < 64; d <<= 1) mx = fmaxf(mx, __shfl_xor(mx, d));
  float sm = 0.f;
  for (int i = o0 + (l >> 3); i < o1; i += 8)
    sm += __expf(scores_csr[(size_t)i * NH + h] - mx);
#pragma unroll
  for (int d = 8; d < 64; d <<= 1) sm += __shfl_xor(sm, d);
  if (l < 8) {
    m[(size_t)n * NH + h] = mx;
    den[(size_t)n * NH + h] = sm;
  }
}

// ---------- gather: weight + accumulate contiguous CSR V rows ----------
__global__ __launch_bounds__(256) void gather2_k(const unsigned short* __restrict__ Vc,
    const float* __restrict__ scores_csr, const float* __restrict__ phi_csr,
    const float* __restrict__ m, const float* __restrict__ den,
    const int* __restrict__ offs, float* __restrict__ accum) {
  int tid = threadIdx.x;
  int n = blockIdx.x * 4 + (tid >> 6);
  int l = tid & 63;
  int h = l >> 3;  // cols 2l,2l+1 -> head (2l)/16
  int o0 = offs[n], o1 = offs[n + 1];
  float mm = m[(size_t)n * NH + h];
  float inv = 1.0f / den[(size_t)n * NH + h];
  float a0 = 0.f, a1 = 0.f;
  const unsigned* base = (const unsigned*)Vc;
  for (int s = o0; s < o1; ++s) {
    float wgt = __expf(scores_csr[(size_t)s * NH + h] - mm) * inv * phi_csr[s];
    unsigned u = base[(size_t)s * 64 + l];
    a0 += wgt * __uint_as_float(u << 16);
    a1 += wgt * __uint_as_float(u & 0xFFFF0000u);
  }
  *(float2*)(accum + (size_t)n * D + l * 2) = make_float2(a0, a1);
}

extern "C" void kernel_launch(void* const* d_in, const int* in_sizes, int n_in,
                              void* d_out, int out_size, void* d_ws, size_t ws_size,
                              hipStream_t stream) {
  const float* x     = (const float*)d_in[0];
  const int*   eidx  = (const int*)d_in[1];
  const int*   jidx  = eidx + NE;
  const float* eattr = (const float*)d_in[2];
  const float* elen  = (const float*)d_in[3];
  const float* W_Q   = (const float*)d_in[4];
  const float* b_Q   = (const float*)d_in[5];
  const float* W_K   = (const float*)d_in[6];
  const float* b_K   = (const float*)d_in[7];
  const float* W_V   = (const float*)d_in[8];
  const float* b_V   = (const float*)d_in[9];
  const float* W_O   = (const float*)d_in[10];
  const float* b_O   = (const float*)d_in[11];
  float* out = (float*)d_out;

  char* ws = (char*)d_ws;
  float* Q          = (float*)ws;            ws += (size_t)NN * D * 4;
  float* scores_csr = (float*)ws;            ws += (size_t)NE * NH * 4;
  float* m          = (float*)ws;            ws += (size_t)NN * NH * 4;
  float* den        = (float*)ws;            ws += (size_t)NN * NH * 4;
  float* accum      = (float*)ws;            ws += (size_t)NN * D * 4;
  int*   cnt        = (int*)ws;              ws += (size_t)NN * 4;
  int*   offs       = (int*)ws;              ws += (size_t)(NN + 1) * 4;
  int*   cursor     = (int*)ws;              ws += (size_t)NN * 4;
  float* phi_csr    = (float*)ws;            ws += (size_t)NE * 4;
  int*   pos        = (int*)ws;              ws += (size_t)NE * 4;
  unsigned short* Vc = (unsigned short*)ws;  // NE*D bf16 = 204.8 MB
  // WKVT (64KB) aliases cursor (200KB): cursor is dead after scatter_k.
  unsigned short* WKVT = (unsigned short*)cursor;

  hipMemsetAsync(cnt, 0, (size_t)NN * 4, stream);

  hist_k<<<NE / 256, 256, 0, stream>>>(jidx, cnt);
  scan_k<<<1, 1024, 0, stream>>>(cnt, offs, cursor);
  scatter_k<<<NE / 256, 256, 0, stream>>>(jidx, cursor, pos);
  wprep_k<<<256, 128, 0, stream>>>(W_K, W_V, WKVT);

  gemm_bias_k<<<(NN + 63) / 64, 256, 0, stream>>>(x, W_Q, b_Q, Q, NN);
  kv_mfma_k<<<NE / 64, 256, 0, stream>>>(eattr, WKVT, b_K, b_V, Q, jidx, elen,
                                         pos, scores_csr, phi_csr, Vc);
  stats2_k<<<NN / 4, 256, 0, stream>>>(scores_csr, offs, m, den);
  gather2_k<<<NN / 4, 256, 0, stream>>>(Vc, scores_csr, phi_csr, m, den, offs, accum);
  gemm_bias_k<<<(NN + 63) / 64, 256, 0, stream>>>(accum, W_O, b_O, out, NN);
}

// Round 2
// 1191.960 us; speedup vs baseline: 1.6742x; 1.2789x over previous
//
#include <hip/hip_runtime.h>
#include <math.h>

// R3: latency-bound kv_mfma fixed: 8 waves x (64x32) tiles, B 2-deep prefetch
// (regs 128->~96), Vt aliased onto As (LDS 35->19KB), launch_bounds(512,4)
// -> 16 waves/CU. phi folded into bf16 V rows. stats+gather fused (finish_k).
#define NN 50000
#define NE 800000
#define D  128
#define NH 8

typedef __attribute__((ext_vector_type(8))) short bf16x8;
typedef __attribute__((ext_vector_type(4))) float f32x4;

__device__ __forceinline__ unsigned short f2bf(float f) {  // RNE
  unsigned x = __float_as_uint(f);
  unsigned r = ((x >> 16) & 1u) + 0x7FFFu;
  return (unsigned short)((x + r) >> 16);
}

// ---------- f32 VALU GEMM (Q and O projections, N=50000) ----------
__device__ __forceinline__ void load_tile(const float* __restrict__ A, int row0, int M,
                                          float (*As)[65], int tid) {
#pragma unroll
  for (int i = 0; i < 8; ++i) {
    int p = tid + i * 256;
    int r = p >> 5;
    int c = (p & 31) << 2;
    float4 v = make_float4(0.f, 0.f, 0.f, 0.f);
    int row = row0 + r;
    if (row < M) v = *(const float4*)(A + (size_t)row * D + c);
    As[c + 0][r] = v.x;
    As[c + 1][r] = v.y;
    As[c + 2][r] = v.z;
    As[c + 3][r] = v.w;
  }
}

__device__ __forceinline__ void gemm_core(const float (*As)[65], const float* __restrict__ B,
                                          int ty, int tx, float acc[4][8]) {
#pragma unroll 8
  for (int k = 0; k < 128; ++k) {
    float a[4];
#pragma unroll
    for (int r = 0; r < 4; ++r) a[r] = As[k][ty * 4 + r];
    float4 b0 = *(const float4*)(B + k * D + tx * 8);
    float4 b1 = *(const float4*)(B + k * D + tx * 8 + 4);
    float b[8] = {b0.x, b0.y, b0.z, b0.w, b1.x, b1.y, b1.z, b1.w};
#pragma unroll
    for (int r = 0; r < 4; ++r)
#pragma unroll
      for (int c = 0; c < 8; ++c) acc[r][c] += a[r] * b[c];
  }
}

__global__ __launch_bounds__(256, 4) void gemm_bias_k(const float* __restrict__ A,
    const float* __restrict__ B, const float* __restrict__ bias,
    float* __restrict__ C, int M) {
  __shared__ float As[128][65];
  int tid = threadIdx.x;
  int row0 = blockIdx.x * 64;
  load_tile(A, row0, M, As, tid);
  __syncthreads();
  int ty = tid >> 4, tx = tid & 15;
  float acc[4][8] = {};
  gemm_core(As, B, ty, tx, acc);
  float4 ba = *(const float4*)(bias + tx * 8);
  float4 bb = *(const float4*)(bias + tx * 8 + 4);
#pragma unroll
  for (int r = 0; r < 4; ++r) {
    int row = row0 + ty * 4 + r;
    if (row < M) {
      float4 o0 = make_float4(acc[r][0] + ba.x, acc[r][1] + ba.y,
                              acc[r][2] + ba.z, acc[r][3] + ba.w);
      float4 o1 = make_float4(acc[r][4] + bb.x, acc[r][5] + bb.y,
                              acc[r][6] + bb.z, acc[r][7] + bb.w);
      *(float4*)(C + (size_t)row * D + tx * 8) = o0;
      *(float4*)(C + (size_t)row * D + tx * 8 + 4) = o1;
    }
  }
}

// ---------- CSR build ----------
__global__ __launch_bounds__(256) void hist_k(const int* __restrict__ jidx,
                                              int* __restrict__ cnt) {
  int e = blockIdx.x * 256 + threadIdx.x;
  atomicAdd(&cnt[jidx[e]], 1);
}

__global__ __launch_bounds__(1024) void scan_k(const int* __restrict__ cnt,
    int* __restrict__ offs, int* __restrict__ cursor) {
  __shared__ int part[1024];
  const int CH = 49;  // 49*1024 >= NN
  int t = threadIdx.x;
  int base = t * CH;
  int s = 0;
  for (int i = 0; i < CH; ++i) {
    int idx = base + i;
    if (idx < NN) s += cnt[idx];
  }
  part[t] = s;
  __syncthreads();
  for (int off = 1; off < 1024; off <<= 1) {
    int v = (t >= off) ? part[t - off] : 0;
    __syncthreads();
    part[t] += v;
    __syncthreads();
  }
  int run = (t == 0) ? 0 : part[t - 1];
  for (int i = 0; i < CH; ++i) {
    int idx = base + i;
    if (idx < NN) {
      offs[idx] = run;
      cursor[idx] = run;
      run += cnt[idx];
    }
  }
  if (t == 1023) offs[NN] = run;
}

__global__ __launch_bounds__(256) void scatter_k(const int* __restrict__ jidx,
    int* __restrict__ cursor, int* __restrict__ pos) {
  int e = blockIdx.x * 256 + threadIdx.x;
  pos[e] = atomicAdd(&cursor[jidx[e]], 1);
}

// ---------- weight prep: WKVT[n][k] = bf16([W_K | W_V][k][n]), n-major ----------
__global__ __launch_bounds__(128) void wprep_k(const float* __restrict__ WK,
    const float* __restrict__ WV, unsigned short* __restrict__ WKVT) {
  int n = blockIdx.x;   // 0..255
  int k = threadIdx.x;  // 0..127
  const float* src = (n < 128) ? WK : WV;
  WKVT[n * 128 + k] = f2bf(src[(size_t)k * 128 + (n & 127)]);
}

// ---------- fused K+V MFMA over edges ----------
// 64 edges x 256 outputs per block, 8 waves each owning a 64x32 sub-tile.
// Waves 0-3: K cols -> per-head Q-dot -> scores (CSR). Waves 4-7: V cols
// (*phi) -> bf16 rows at CSR slots via LDS transpose aliased onto As.
__global__ __launch_bounds__(512, 4) void kv_mfma_k(
    const float* __restrict__ EA, const unsigned short* __restrict__ WKVT,
    const float* __restrict__ bK, const float* __restrict__ bV,
    const float* __restrict__ Q, const int* __restrict__ jidx,
    const float* __restrict__ elen, const int* __restrict__ pos,
    float* __restrict__ scores_csr, unsigned short* __restrict__ Vc) {
  __shared__ unsigned short As[64 * 128];  // 16KB bf16 A tile; reused as Vt
  __shared__ float St[64][8];              // scores staging
  __shared__ float Sphi[64];
  __shared__ int Spos[64];
  __shared__ int Sjn[64];
  int tid = threadIdx.x;
  int e0 = blockIdx.x * 64;

  // stage A: f32 -> bf16, swizzle ushort idx ^ ((row&7)<<3)
#pragma unroll
  for (int i = 0; i < 2; ++i) {
    int p = tid + i * 512;
    int r = p >> 4;  // row 0..63
    int c = p & 15;  // 8-col chunk
    const float* src = EA + (size_t)(e0 + r) * D + c * 8;
    float4 v0 = *(const float4*)src;
    float4 v1 = *(const float4*)(src + 4);
    unsigned q0 = f2bf(v0.x) | ((unsigned)f2bf(v0.y) << 16);
    unsigned q1 = f2bf(v0.z) | ((unsigned)f2bf(v0.w) << 16);
    unsigned q2 = f2bf(v1.x) | ((unsigned)f2bf(v1.y) << 16);
    unsigned q3 = f2bf(v1.z) | ((unsigned)f2bf(v1.w) << 16);
    *(uint4*)(As + r * 128 + ((c * 8) ^ ((r & 7) << 3))) = make_uint4(q0, q1, q2, q3);
  }
  if (tid < 64) {
    Spos[tid] = pos[e0 + tid];
    Sjn[tid] = jidx[e0 + tid];
    float ln = elen[e0 + tid];
    Sphi[tid] = 0.5f * (__cosf(ln * 0.628318530717958647f) + 1.0f);  // pi/5
  }

  int w = tid >> 6, l = tid & 63;
  int lr = l & 15, lg = l >> 4;
  // wave w covers WKVT cols [w*32, w*32+32): w<4 -> K heads 2w,2w+1; w>=4 -> V
  const unsigned short* wb = WKVT + (size_t)(w * 32 + lr) * 128 + lg * 8;
  bf16x8 Bcur0 = *(const bf16x8*)(wb);
  bf16x8 Bcur1 = *(const bf16x8*)(wb + 16 * 128);
  f32x4 acc[4][2] = {};
  __syncthreads();

#pragma unroll
  for (int ks = 0; ks < 4; ++ks) {
    bf16x8 Bn0, Bn1;
    if (ks < 3) {
      Bn0 = *(const bf16x8*)(wb + (ks + 1) * 32);
      Bn1 = *(const bf16x8*)(wb + 16 * 128 + (ks + 1) * 32);
    }
#pragma unroll
    for (int mi = 0; mi < 4; ++mi) {
      int row = mi * 16 + lr;
      int ku = ks * 32 + lg * 8;
      bf16x8 a = *(const bf16x8*)(As + row * 128 + (ku ^ ((row & 7) << 3)));
      acc[mi][0] = __builtin_amdgcn_mfma_f32_16x16x32_bf16(a, Bcur0, acc[mi][0], 0, 0, 0);
      acc[mi][1] = __builtin_amdgcn_mfma_f32_16x16x32_bf16(a, Bcur1, acc[mi][1], 0, 0, 0);
    }
    if (ks < 3) { Bcur0 = Bn0; Bcur1 = Bn1; }
  }
  __syncthreads();  // all As reads done -> safe to reuse As as Vt

  // C layout: col = lane&15, row = (lane>>4)*4 + reg
  if (w < 4) {  // K waves: scores for heads 2w, 2w+1
    float bk0 = bK[w * 32 + lr], bk1 = bK[w * 32 + 16 + lr];
#pragma unroll
    for (int mi = 0; mi < 4; ++mi)
#pragma unroll
      for (int r = 0; r < 4; ++r) {
        int erow = mi * 16 + lg * 4 + r;
        int jn = Sjn[erow];
        const float* qrow = Q + (size_t)jn * D + w * 32;
        float q0 = qrow[lr], q1 = qrow[16 + lr];
        float t0 = (acc[mi][0][r] + bk0) * q0;
        float t1 = (acc[mi][1][r] + bk1) * q1;
        t0 += __shfl_xor(t0, 1); t1 += __shfl_xor(t1, 1);
        t0 += __shfl_xor(t0, 2); t1 += __shfl_xor(t1, 2);
        t0 += __shfl_xor(t0, 4); t1 += __shfl_xor(t1, 4);
        t0 += __shfl_xor(t0, 8); t1 += __shfl_xor(t1, 8);
        if (lr == 0) {
          St[erow][w * 2] = t0 * 0.25f;
          St[erow][w * 2 + 1] = t1 * 0.25f;
        }
      }
  } else {  // V waves: (V+bias)*phi -> bf16 into Vt(=As), swizzled
    float bv0 = bV[(w - 4) * 32 + lr], bv1 = bV[(w - 4) * 32 + 16 + lr];
    int c0 = (w - 4) * 32 + lr;
#pragma unroll
    for (int mi = 0; mi < 4; ++mi)
#pragma unroll
      for (int r = 0; r < 4; ++r) {
        int row = mi * 16 + lg * 4 + r;
        float ph = Sphi[row];
        int sw = (row & 7) << 3;
        As[row * 128 + (c0 ^ sw)] = f2bf((acc[mi][0][r] + bv0) * ph);
        As[row * 128 + ((c0 + 16) ^ sw)] = f2bf((acc[mi][1][r] + bv1) * ph);
      }
  }
  __syncthreads();

  // scores out: 64 rows x 32B at CSR slots
  if (tid < 128) {
    int row = tid >> 1, half = tid & 1;
    float4 s = *(const float4*)(&St[row][half * 4]);
    *(float4*)(scores_csr + (size_t)Spos[row] * NH + half * 4) = s;
  }
  // V out: 64 rows x 256B at CSR slots, 16B chunks
#pragma unroll
  for (int i = 0; i < 2; ++i) {
    int p = tid + i * 512;
    int row = p >> 4, c = p & 15;
    uint4 v = *(const uint4*)(As + row * 128 + ((c * 8) ^ ((row & 7) << 3)));
    *(uint4*)(Vc + (size_t)Spos[row] * D + c * 8) = v;
  }
}

// ---------- fused softmax stats + weighted gather (per node, CSR streams) ----
__global__ __launch_bounds__(256) void finish_k(const unsigned short* __restrict__ Vc,
    const float* __restrict__ scores_csr, const int* __restrict__ offs,
    float* __restrict__ accum) {
  int tid = threadIdx.x;
  int n = blockIdx.x * 4 + (tid >> 6);  // one 64-lane wave per node
  int l = tid & 63;
  int o0 = offs[n], o1 = offs[n + 1];
  // stats phase: lane handles head l&7, edges stride 8
  int hs = l & 7;
  float mx = -INFINITY;
  for (int i = o0 + (l >> 3); i < o1; i += 8)
    mx = fmaxf(mx, scores_csr[(size_t)i * NH + hs]);
#pragma unroll
  for (int d = 8; d < 64; d <<= 1) mx = fmaxf(mx, __shfl_xor(mx, d));
  float sm = 0.f;
  for (int i = o0 + (l >> 3); i < o1; i += 8)
    sm += __expf(scores_csr[(size_t)i * NH + hs] - mx);
#pragma unroll
  for (int d = 8; d < 64; d <<= 1) sm += __shfl_xor(sm, d);
  // gather phase: lane handles cols 2l,2l+1 -> head l>>3 (lane l>>3 holds it)
  int hg = l >> 3;
  float mm = __shfl(mx, hg);
  float inv = 1.0f / __shfl(sm, hg);
  float a0 = 0.f, a1 = 0.f;
  const unsigned* base = (const unsigned*)Vc;
  for (int s = o0; s < o1; ++s) {
    float wgt = __expf(scores_csr[(size_t)s * NH + hg] - mm) * inv;
    unsigned u = base[(size_t)s * 64 + l];
    a0 += wgt * __uint_as_float(u << 16);
    a1 += wgt * __uint_as_float(u & 0xFFFF0000u);
  }
  *(float2*)(accum + (size_t)n * D + l * 2) = make_float2(a0, a1);
}

extern "C" void kernel_launch(void* const* d_in, const int* in_sizes, int n_in,
                              void* d_out, int out_size, void* d_ws, size_t ws_size,
                              hipStream_t stream) {
  const float* x     = (const float*)d_in[0];
  const int*   eidx  = (const int*)d_in[1];
  const int*   jidx  = eidx + NE;
  const float* eattr = (const float*)d_in[2];
  const float* elen  = (const float*)d_in[3];
  const float* W_Q   = (const float*)d_in[4];
  const float* b_Q   = (const float*)d_in[5];
  const float* W_K   = (const float*)d_in[6];
  const float* b_K   = (const float*)d_in[7];
  const float* W_V   = (const float*)d_in[8];
  const float* b_V   = (const float*)d_in[9];
  const float* W_O   = (const float*)d_in[10];
  const float* b_O   = (const float*)d_in[11];
  float* out = (float*)d_out;

  char* ws = (char*)d_ws;
  float* Q          = (float*)ws;            ws += (size_t)NN * D * 4;
  float* scores_csr = (float*)ws;            ws += (size_t)NE * NH * 4;
  float* accum      = (float*)ws;            ws += (size_t)NN * D * 4;
  int*   cnt        = (int*)ws;              ws += (size_t)NN * 4;
  int*   offs       = (int*)ws;              ws += (size_t)(NN + 1) * 4;
  int*   cursor     = (int*)ws;              ws += (size_t)NN * 4;
  int*   pos        = (int*)ws;              ws += (size_t)NE * 4;
  unsigned short* Vc = (unsigned short*)ws;  // NE*D bf16 = 204.8 MB
  // WKVT (64KB) aliases cursor (200KB): cursor is dead after scatter_k.
  unsigned short* WKVT = (unsigned short*)cursor;

  hipMemsetAsync(cnt, 0, (size_t)NN * 4, stream);

  hist_k<<<NE / 256, 256, 0, stream>>>(jidx, cnt);
  scan_k<<<1, 1024, 0, stream>>>(cnt, offs, cursor);
  scatter_k<<<NE / 256, 256, 0, stream>>>(jidx, cursor, pos);
  wprep_k<<<256, 128, 0, stream>>>(W_K, W_V, WKVT);

  gemm_bias_k<<<(NN + 63) / 64, 256, 0, stream>>>(x, W_Q, b_Q, Q, NN);
  kv_mfma_k<<<NE / 64, 512, 0, stream>>>(eattr, WKVT, b_K, b_V, Q, jidx, elen,
                                         pos, scores_csr, Vc);
  finish_k<<<NN / 4, 256, 0, stream>>>(Vc, scores_csr, offs, accum);
  gemm_bias_k<<<(NN + 63) / 64, 256, 0, stream>>>(accum, W_O, b_O, out, NN);
}

// Round 4
// 1172.611 us; speedup vs baseline: 1.7018x; 1.0165x over previous
//
#include <hip/hip_runtime.h>
#include <math.h>

// R5 (= R4 resubmit after infra failure): kv_mfma launch_bounds(512,4)->(512,8)
// (16->32 waves/CU; VGPR=44, LDS=19.4KB both allow 4 blocks/CU). finish_k ->
// single-pass online softmax. gemm_bias kept at (256,4) (LDS caps it anyway).
#define NN 50000
#define NE 800000
#define D  128
#define NH 8

typedef __attribute__((ext_vector_type(8))) short bf16x8;
typedef __attribute__((ext_vector_type(4))) float f32x4;

__device__ __forceinline__ unsigned short f2bf(float f) {  // RNE
  unsigned x = __float_as_uint(f);
  unsigned r = ((x >> 16) & 1u) + 0x7FFFu;
  return (unsigned short)((x + r) >> 16);
}

// ---------- f32 VALU GEMM (Q and O projections, N=50000) ----------
__device__ __forceinline__ void load_tile(const float* __restrict__ A, int row0, int M,
                                          float (*As)[65], int tid) {
#pragma unroll
  for (int i = 0; i < 8; ++i) {
    int p = tid + i * 256;
    int r = p >> 5;
    int c = (p & 31) << 2;
    float4 v = make_float4(0.f, 0.f, 0.f, 0.f);
    int row = row0 + r;
    if (row < M) v = *(const float4*)(A + (size_t)row * D + c);
    As[c + 0][r] = v.x;
    As[c + 1][r] = v.y;
    As[c + 2][r] = v.z;
    As[c + 3][r] = v.w;
  }
}

__device__ __forceinline__ void gemm_core(const float (*As)[65], const float* __restrict__ B,
                                          int ty, int tx, float acc[4][8]) {
#pragma unroll 8
  for (int k = 0; k < 128; ++k) {
    float a[4];
#pragma unroll
    for (int r = 0; r < 4; ++r) a[r] = As[k][ty * 4 + r];
    float4 b0 = *(const float4*)(B + k * D + tx * 8);
    float4 b1 = *(const float4*)(B + k * D + tx * 8 + 4);
    float b[8] = {b0.x, b0.y, b0.z, b0.w, b1.x, b1.y, b1.z, b1.w};
#pragma unroll
    for (int r = 0; r < 4; ++r)
#pragma unroll
      for (int c = 0; c < 8; ++c) acc[r][c] += a[r] * b[c];
  }
}

__global__ __launch_bounds__(256, 4) void gemm_bias_k(const float* __restrict__ A,
    const float* __restrict__ B, const float* __restrict__ bias,
    float* __restrict__ C, int M) {
  __shared__ float As[128][65];
  int tid = threadIdx.x;
  int row0 = blockIdx.x * 64;
  load_tile(A, row0, M, As, tid);
  __syncthreads();
  int ty = tid >> 4, tx = tid & 15;
  float acc[4][8] = {};
  gemm_core(As, B, ty, tx, acc);
  float4 ba = *(const float4*)(bias + tx * 8);
  float4 bb = *(const float4*)(bias + tx * 8 + 4);
#pragma unroll
  for (int r = 0; r < 4; ++r) {
    int row = row0 + ty * 4 + r;
    if (row < M) {
      float4 o0 = make_float4(acc[r][0] + ba.x, acc[r][1] + ba.y,
                              acc[r][2] + ba.z, acc[r][3] + ba.w);
      float4 o1 = make_float4(acc[r][4] + bb.x, acc[r][5] + bb.y,
                              acc[r][6] + bb.z, acc[r][7] + bb.w);
      *(float4*)(C + (size_t)row * D + tx * 8) = o0;
      *(float4*)(C + (size_t)row * D + tx * 8 + 4) = o1;
    }
  }
}

// ---------- CSR build ----------
__global__ __launch_bounds__(256) void hist_k(const int* __restrict__ jidx,
                                              int* __restrict__ cnt) {
  int e = blockIdx.x * 256 + threadIdx.x;
  atomicAdd(&cnt[jidx[e]], 1);
}

__global__ __launch_bounds__(1024) void scan_k(const int* __restrict__ cnt,
    int* __restrict__ offs, int* __restrict__ cursor) {
  __shared__ int part[1024];
  const int CH = 49;  // 49*1024 >= NN
  int t = threadIdx.x;
  int base = t * CH;
  int s = 0;
  for (int i = 0; i < CH; ++i) {
    int idx = base + i;
    if (idx < NN) s += cnt[idx];
  }
  part[t] = s;
  __syncthreads();
  for (int off = 1; off < 1024; off <<= 1) {
    int v = (t >= off) ? part[t - off] : 0;
    __syncthreads();
    part[t] += v;
    __syncthreads();
  }
  int run = (t == 0) ? 0 : part[t - 1];
  for (int i = 0; i < CH; ++i) {
    int idx = base + i;
    if (idx < NN) {
      offs[idx] = run;
      cursor[idx] = run;
      run += cnt[idx];
    }
  }
  if (t == 1023) offs[NN] = run;
}

__global__ __launch_bounds__(256) void scatter_k(const int* __restrict__ jidx,
    int* __restrict__ cursor, int* __restrict__ pos) {
  int e = blockIdx.x * 256 + threadIdx.x;
  pos[e] = atomicAdd(&cursor[jidx[e]], 1);
}

// ---------- weight prep: WKVT[n][k] = bf16([W_K | W_V][k][n]), n-major ----------
__global__ __launch_bounds__(128) void wprep_k(const float* __restrict__ WK,
    const float* __restrict__ WV, unsigned short* __restrict__ WKVT) {
  int n = blockIdx.x;   // 0..255
  int k = threadIdx.x;  // 0..127
  const float* src = (n < 128) ? WK : WV;
  WKVT[n * 128 + k] = f2bf(src[(size_t)k * 128 + (n & 127)]);
}

// ---------- fused K+V MFMA over edges ----------
// 64 edges x 256 outputs per block, 8 waves each owning a 64x32 sub-tile.
// Waves 0-3: K cols -> per-head Q-dot -> scores (CSR). Waves 4-7: V cols
// (*phi) -> bf16 rows at CSR slots via LDS transpose aliased onto As.
__global__ __launch_bounds__(512, 8) void kv_mfma_k(
    const float* __restrict__ EA, const unsigned short* __restrict__ WKVT,
    const float* __restrict__ bK, const float* __restrict__ bV,
    const float* __restrict__ Q, const int* __restrict__ jidx,
    const float* __restrict__ elen, const int* __restrict__ pos,
    float* __restrict__ scores_csr, unsigned short* __restrict__ Vc) {
  __shared__ unsigned short As[64 * 128];  // 16KB bf16 A tile; reused as Vt
  __shared__ float St[64][8];              // scores staging
  __shared__ float Sphi[64];
  __shared__ int Spos[64];
  __shared__ int Sjn[64];
  int tid = threadIdx.x;
  int e0 = blockIdx.x * 64;

  if (tid < 64) {
    Spos[tid] = pos[e0 + tid];
    Sjn[tid] = jidx[e0 + tid];
    float ln = elen[e0 + tid];
    Sphi[tid] = 0.5f * (__cosf(ln * 0.628318530717958647f) + 1.0f);  // pi/5
  }
  // stage A: f32 -> bf16, swizzle ushort idx ^ ((row&7)<<3)
#pragma unroll
  for (int i = 0; i < 2; ++i) {
    int p = tid + i * 512;
    int r = p >> 4;  // row 0..63
    int c = p & 15;  // 8-col chunk
    const float* src = EA + (size_t)(e0 + r) * D + c * 8;
    float4 v0 = *(const float4*)src;
    float4 v1 = *(const float4*)(src + 4);
    unsigned q0 = f2bf(v0.x) | ((unsigned)f2bf(v0.y) << 16);
    unsigned q1 = f2bf(v0.z) | ((unsigned)f2bf(v0.w) << 16);
    unsigned q2 = f2bf(v1.x) | ((unsigned)f2bf(v1.y) << 16);
    unsigned q3 = f2bf(v1.z) | ((unsigned)f2bf(v1.w) << 16);
    *(uint4*)(As + r * 128 + ((c * 8) ^ ((r & 7) << 3))) = make_uint4(q0, q1, q2, q3);
  }

  int w = tid >> 6, l = tid & 63;
  int lr = l & 15, lg = l >> 4;
  // wave w covers WKVT cols [w*32, w*32+32): w<4 -> K heads 2w,2w+1; w>=4 -> V
  const unsigned short* wb = WKVT + (size_t)(w * 32 + lr) * 128 + lg * 8;
  bf16x8 Bcur0 = *(const bf16x8*)(wb);
  bf16x8 Bcur1 = *(const bf16x8*)(wb + 16 * 128);
  f32x4 acc[4][2] = {};
  __syncthreads();

#pragma unroll
  for (int ks = 0; ks < 4; ++ks) {
    bf16x8 Bn0, Bn1;
    if (ks < 3) {
      Bn0 = *(const bf16x8*)(wb + (ks + 1) * 32);
      Bn1 = *(const bf16x8*)(wb + 16 * 128 + (ks + 1) * 32);
    }
#pragma unroll
    for (int mi = 0; mi < 4; ++mi) {
      int row = mi * 16 + lr;
      int ku = ks * 32 + lg * 8;
      bf16x8 a = *(const bf16x8*)(As + row * 128 + (ku ^ ((row & 7) << 3)));
      acc[mi][0] = __builtin_amdgcn_mfma_f32_16x16x32_bf16(a, Bcur0, acc[mi][0], 0, 0, 0);
      acc[mi][1] = __builtin_amdgcn_mfma_f32_16x16x32_bf16(a, Bcur1, acc[mi][1], 0, 0, 0);
    }
    if (ks < 3) { Bcur0 = Bn0; Bcur1 = Bn1; }
  }
  __syncthreads();  // all As reads done -> safe to reuse As as Vt

  // C layout: col = lane&15, row = (lane>>4)*4 + reg
  if (w < 4) {  // K waves: scores for heads 2w, 2w+1
    float bk0 = bK[w * 32 + lr], bk1 = bK[w * 32 + 16 + lr];
#pragma unroll
    for (int mi = 0; mi < 4; ++mi)
#pragma unroll
      for (int r = 0; r < 4; ++r) {
        int erow = mi * 16 + lg * 4 + r;
        int jn = Sjn[erow];
        const float* qrow = Q + (size_t)jn * D + w * 32;
        float q0 = qrow[lr], q1 = qrow[16 + lr];
        float t0 = (acc[mi][0][r] + bk0) * q0;
        float t1 = (acc[mi][1][r] + bk1) * q1;
        t0 += __shfl_xor(t0, 1); t1 += __shfl_xor(t1, 1);
        t0 += __shfl_xor(t0, 2); t1 += __shfl_xor(t1, 2);
        t0 += __shfl_xor(t0, 4); t1 += __shfl_xor(t1, 4);
        t0 += __shfl_xor(t0, 8); t1 += __shfl_xor(t1, 8);
        if (lr == 0) {
          St[erow][w * 2] = t0 * 0.25f;
          St[erow][w * 2 + 1] = t1 * 0.25f;
        }
      }
  } else {  // V waves: (V+bias)*phi -> bf16 into Vt(=As), swizzled
    float bv0 = bV[(w - 4) * 32 + lr], bv1 = bV[(w - 4) * 32 + 16 + lr];
    int c0 = (w - 4) * 32 + lr;
#pragma unroll
    for (int mi = 0; mi < 4; ++mi)
#pragma unroll
      for (int r = 0; r < 4; ++r) {
        int row = mi * 16 + lg * 4 + r;
        float ph = Sphi[row];
        int sw = (row & 7) << 3;
        As[row * 128 + (c0 ^ sw)] = f2bf((acc[mi][0][r] + bv0) * ph);
        As[row * 128 + ((c0 + 16) ^ sw)] = f2bf((acc[mi][1][r] + bv1) * ph);
      }
  }
  __syncthreads();

  // scores out: 64 rows x 32B at CSR slots
  if (tid < 128) {
    int row = tid >> 1, half = tid & 1;
    float4 s = *(const float4*)(&St[row][half * 4]);
    *(float4*)(scores_csr + (size_t)Spos[row] * NH + half * 4) = s;
  }
  // V out: 64 rows x 256B at CSR slots, 16B chunks
#pragma unroll
  for (int i = 0; i < 2; ++i) {
    int p = tid + i * 512;
    int row = p >> 4, c = p & 15;
    uint4 v = *(const uint4*)(As + row * 128 + ((c * 8) ^ ((row & 7) << 3)));
    *(uint4*)(Vc + (size_t)Spos[row] * D + c * 8) = v;
  }
}

// ---------- single-pass online-softmax gather over contiguous CSR rows ------
__global__ __launch_bounds__(256) void finish_k(const unsigned short* __restrict__ Vc,
    const float* __restrict__ scores_csr, const int* __restrict__ offs,
    float* __restrict__ accum) {
  int tid = threadIdx.x;
  int n = blockIdx.x * 4 + (tid >> 6);  // one 64-lane wave per node
  int l = tid & 63;
  int hg = l >> 3;  // lane covers cols 2l,2l+1 -> head l/8
  int o0 = offs[n], o1 = offs[n + 1];
  float m = -INFINITY, den = 0.f, a0 = 0.f, a1 = 0.f;
  const unsigned* base = (const unsigned*)Vc;
  for (int s = o0; s < o1; ++s) {
    float sc = scores_csr[(size_t)s * NH + hg];
    unsigned u = base[(size_t)s * 64 + l];
    float nm = fmaxf(m, sc);
    float c = __expf(m - nm);   // 1 if max unchanged, 0 on first iter
    float wg = __expf(sc - nm);
    den = den * c + wg;
    a0 = a0 * c + wg * __uint_as_float(u << 16);
    a1 = a1 * c + wg * __uint_as_float(u & 0xFFFF0000u);
    m = nm;
  }
  float inv = (den > 0.f) ? 1.0f / den : 0.f;
  *(float2*)(accum + (size_t)n * D + l * 2) = make_float2(a0 * inv, a1 * inv);
}

extern "C" void kernel_launch(void* const* d_in, const int* in_sizes, int n_in,
                              void* d_out, int out_size, void* d_ws, size_t ws_size,
                              hipStream_t stream) {
  const float* x     = (const float*)d_in[0];
  const int*   eidx  = (const int*)d_in[1];
  const int*   jidx  = eidx + NE;
  const float* eattr = (const float*)d_in[2];
  const float* elen  = (const float*)d_in[3];
  const float* W_Q   = (const float*)d_in[4];
  const float* b_Q   = (const float*)d_in[5];
  const float* W_K   = (const float*)d_in[6];
  const float* b_K   = (const float*)d_in[7];
  const float* W_V   = (const float*)d_in[8];
  const float* b_V   = (const float*)d_in[9];
  const float* W_O   = (const float*)d_in[10];
  const float* b_O   = (const float*)d_in[11];
  float* out = (float*)d_out;

  char* ws = (char*)d_ws;
  float* Q          = (float*)ws;            ws += (size_t)NN * D * 4;
  float* scores_csr = (float*)ws;            ws += (size_t)NE * NH * 4;
  float* accum      = (float*)ws;            ws += (size_t)NN * D * 4;
  int*   cnt        = (int*)ws;              ws += (size_t)NN * 4;
  int*   offs       = (int*)ws;              ws += (size_t)(NN + 1) * 4;
  int*   cursor     = (int*)ws;              ws += (size_t)NN * 4;
  int*   pos        = (int*)ws;              ws += (size_t)NE * 4;
  unsigned short* Vc = (unsigned short*)ws;  // NE*D bf16 = 204.8 MB
  // WKVT (64KB) aliases cursor (200KB): cursor is dead after scatter_k.
  unsigned short* WKVT = (unsigned short*)cursor;

  hipMemsetAsync(cnt, 0, (size_t)NN * 4, stream);

  hist_k<<<NE / 256, 256, 0, stream>>>(jidx, cnt);
  scan_k<<<1, 1024, 0, stream>>>(cnt, offs, cursor);
  scatter_k<<<NE / 256, 256, 0, stream>>>(jidx, cursor, pos);
  wprep_k<<<256, 128, 0, stream>>>(W_K, W_V, WKVT);

  gemm_bias_k<<<(NN + 63) / 64, 256, 0, stream>>>(x, W_Q, b_Q, Q, NN);
  kv_mfma_k<<<NE / 64, 512, 0, stream>>>(eattr, WKVT, b_K, b_V, Q, jidx, elen,
                                         pos, scores_csr, Vc);
  finish_k<<<NN / 4, 256, 0, stream>>>(Vc, scores_csr, offs, accum);
  gemm_bias_k<<<(NN + 63) / 64, 256, 0, stream>>>(accum, W_O, b_O, out, NN);
}

// Round 5
// 1042.237 us; speedup vs baseline: 1.9147x; 1.1251x over previous
//
#include <hip/hip_runtime.h>
#include <math.h>

// R6: kill the scatter->global->gather round-trip. No-max softmax (scores are
// O(10)) => segmented softmax becomes segmented SUM. kvagg_k gathers 64
// CSR-ordered edges, MFMA K|V, computes ex=exp(s) and v*phi, reduces node-runs
// in LDS, atomicAdds per-node partials Pnum[n][128], Pden[n][8]. Vc/scores/
// finish_k eliminated (~460MB traffic + write amplification). O-GEMM divides
// by den during A-load.
#define NN 50000
#define NE 800000
#define D  128
#define NH 8

typedef __attribute__((ext_vector_type(8))) short bf16x8;
typedef __attribute__((ext_vector_type(4))) float f32x4;

__device__ __forceinline__ unsigned short f2bf(float f) {  // RNE
  unsigned x = __float_as_uint(f);
  unsigned r = ((x >> 16) & 1u) + 0x7FFFu;
  return (unsigned short)((x + r) >> 16);
}

// ---------- f32 VALU GEMM core (Q and O projections, N=50000) ----------
__device__ __forceinline__ void gemm_core(const float (*As)[65], const float* __restrict__ B,
                                          int ty, int tx, float acc[4][8]) {
#pragma unroll 8
  for (int k = 0; k < 128; ++k) {
    float a[4];
#pragma unroll
    for (int r = 0; r < 4; ++r) a[r] = As[k][ty * 4 + r];
    float4 b0 = *(const float4*)(B + k * D + tx * 8);
    float4 b1 = *(const float4*)(B + k * D + tx * 8 + 4);
    float b[8] = {b0.x, b0.y, b0.z, b0.w, b1.x, b1.y, b1.z, b1.w};
#pragma unroll
    for (int r = 0; r < 4; ++r)
#pragma unroll
      for (int c = 0; c < 8; ++c) acc[r][c] += a[r] * b[c];
  }
}

__device__ __forceinline__ void gemm_epilogue(float acc[4][8], const float* __restrict__ bias,
                                              float* __restrict__ C, int row0, int ty, int tx,
                                              int M) {
  float4 ba = *(const float4*)(bias + tx * 8);
  float4 bb = *(const float4*)(bias + tx * 8 + 4);
#pragma unroll
  for (int r = 0; r < 4; ++r) {
    int row = row0 + ty * 4 + r;
    if (row < M) {
      float4 o0 = make_float4(acc[r][0] + ba.x, acc[r][1] + ba.y,
                              acc[r][2] + ba.z, acc[r][3] + ba.w);
      float4 o1 = make_float4(acc[r][4] + bb.x, acc[r][5] + bb.y,
                              acc[r][6] + bb.z, acc[r][7] + bb.w);
      *(float4*)(C + (size_t)row * D + tx * 8) = o0;
      *(float4*)(C + (size_t)row * D + tx * 8 + 4) = o1;
    }
  }
}

__global__ __launch_bounds__(256, 4) void gemm_bias_k(const float* __restrict__ A,
    const float* __restrict__ B, const float* __restrict__ bias,
    float* __restrict__ C, int M) {
  __shared__ float As[128][65];
  int tid = threadIdx.x;
  int row0 = blockIdx.x * 64;
#pragma unroll
  for (int i = 0; i < 8; ++i) {
    int p = tid + i * 256;
    int r = p >> 5;
    int c = (p & 31) << 2;
    float4 v = make_float4(0.f, 0.f, 0.f, 0.f);
    int row = row0 + r;
    if (row < M) v = *(const float4*)(A + (size_t)row * D + c);
    As[c + 0][r] = v.x; As[c + 1][r] = v.y; As[c + 2][r] = v.z; As[c + 3][r] = v.w;
  }
  __syncthreads();
  int ty = tid >> 4, tx = tid & 15;
  float acc[4][8] = {};
  gemm_core(As, B, ty, tx, acc);
  gemm_epilogue(acc, bias, C, row0, ty, tx, M);
}

// O-GEMM with per-head normalization folded into the A-tile load.
__global__ __launch_bounds__(256, 4) void gemm_norm_bias_k(const float* __restrict__ A,
    const float* __restrict__ den, const float* __restrict__ B,
    const float* __restrict__ bias, float* __restrict__ C, int M) {
  __shared__ float As[128][65];
  int tid = threadIdx.x;
  int row0 = blockIdx.x * 64;
#pragma unroll
  for (int i = 0; i < 8; ++i) {
    int p = tid + i * 256;
    int r = p >> 5;
    int c = (p & 31) << 2;  // c..c+3 within one 16-col head block
    float4 v = make_float4(0.f, 0.f, 0.f, 0.f);
    int row = row0 + r;
    if (row < M) {
      v = *(const float4*)(A + (size_t)row * D + c);
      float dd = den[(size_t)row * NH + (c >> 4)];
      float inv = (dd > 0.f) ? 1.0f / dd : 0.f;
      v.x *= inv; v.y *= inv; v.z *= inv; v.w *= inv;
    }
    As[c + 0][r] = v.x; As[c + 1][r] = v.y; As[c + 2][r] = v.z; As[c + 3][r] = v.w;
  }
  __syncthreads();
  int ty = tid >> 4, tx = tid & 15;
  float acc[4][8] = {};
  gemm_core(As, B, ty, tx, acc);
  gemm_epilogue(acc, bias, C, row0, ty, tx, M);
}

// ---------- CSR build ----------
__global__ __launch_bounds__(256) void hist_k(const int* __restrict__ jidx,
                                              int* __restrict__ cnt) {
  int e = blockIdx.x * 256 + threadIdx.x;
  atomicAdd(&cnt[jidx[e]], 1);
}

__global__ __launch_bounds__(1024) void scan_k(const int* __restrict__ cnt,
    int* __restrict__ offs, int* __restrict__ cursor) {
  __shared__ int part[1024];
  const int CH = 49;  // 49*1024 >= NN
  int t = threadIdx.x;
  int base = t * CH;
  int s = 0;
  for (int i = 0; i < CH; ++i) {
    int idx = base + i;
    if (idx < NN) s += cnt[idx];
  }
  part[t] = s;
  __syncthreads();
  for (int off = 1; off < 1024; off <<= 1) {
    int v = (t >= off) ? part[t - off] : 0;
    __syncthreads();
    part[t] += v;
    __syncthreads();
  }
  int run = (t == 0) ? 0 : part[t - 1];
  for (int i = 0; i < CH; ++i) {
    int idx = base + i;
    if (idx < NN) {
      offs[idx] = run;
      cursor[idx] = run;
      run += cnt[idx];
    }
  }
  if (t == 1023) offs[NN] = run;
}

__global__ __launch_bounds__(256) void scatter_k(const int* __restrict__ jidx,
    int* __restrict__ cursor, int* __restrict__ elist) {
  int e = blockIdx.x * 256 + threadIdx.x;
  int p = atomicAdd(&cursor[jidx[e]], 1);
  elist[p] = e;
}

// ---------- weight prep: WKVT[n][k] = bf16([W_K | W_V][k][n]), n-major ----------
__global__ __launch_bounds__(128) void wprep_k(const float* __restrict__ WK,
    const float* __restrict__ WV, unsigned short* __restrict__ WKVT) {
  int n = blockIdx.x;   // 0..255
  int k = threadIdx.x;  // 0..127
  const float* src = (n < 128) ? WK : WV;
  WKVT[n * 128 + k] = f2bf(src[(size_t)k * 128 + (n & 127)]);
}

// ---------- fused K+V MFMA + segmented aggregation over CSR-ordered edges ----
// Block = 64 CSR-consecutive edges (node-contiguous runs). 8 waves x 64x32
// MFMA sub-tiles. Waves 0-3: K -> Q-dot -> ex=exp(s) in LDS. Waves 4-7:
// (V+bias)*phi -> f32 LDS. Then per-run column sums -> atomicAdd partials.
__global__ __launch_bounds__(512, 8) void kvagg_k(
    const float* __restrict__ EA, const unsigned short* __restrict__ WKVT,
    const float* __restrict__ bK, const float* __restrict__ bV,
    const float* __restrict__ Q, const int* __restrict__ jidx,
    const float* __restrict__ elen, const int* __restrict__ elist,
    float* __restrict__ Pnum, float* __restrict__ Pden) {
  __shared__ __align__(16) float VtF[64][132];  // 33.8KB; front 16KB aliased as bf16 A tile
  __shared__ float Sex[64][8];
  __shared__ float Sphi[64];
  __shared__ int Sjn[64];
  __shared__ int Sed[64];
  __shared__ int runStart[65];
  __shared__ int runNode[64];
  __shared__ int nrunsS;
  unsigned short* As = (unsigned short*)&VtF[0][0];

  int tid = threadIdx.x;
  int e0 = blockIdx.x * 64;

  if (tid < 64) {
    int eo = elist[e0 + tid];
    Sed[tid] = eo;
    Sjn[tid] = jidx[eo];
    float ln = elen[eo];
    Sphi[tid] = 0.5f * (__cosf(ln * 0.628318530717958647f) + 1.0f);  // pi/5
  }
  __syncthreads();

  // stage gathered EA rows: f32 -> bf16, swizzle ushort idx ^ ((row&7)<<3)
#pragma unroll
  for (int i = 0; i < 2; ++i) {
    int p = tid + i * 512;
    int r = p >> 4;  // row 0..63
    int c = p & 15;  // 8-col chunk
    const float* src = EA + (size_t)Sed[r] * D + c * 8;
    float4 v0 = *(const float4*)src;
    float4 v1 = *(const float4*)(src + 4);
    unsigned q0 = f2bf(v0.x) | ((unsigned)f2bf(v0.y) << 16);
    unsigned q1 = f2bf(v0.z) | ((unsigned)f2bf(v0.w) << 16);
    unsigned q2 = f2bf(v1.x) | ((unsigned)f2bf(v1.y) << 16);
    unsigned q3 = f2bf(v1.z) | ((unsigned)f2bf(v1.w) << 16);
    *(uint4*)(As + r * 128 + ((c * 8) ^ ((r & 7) << 3))) = make_uint4(q0, q1, q2, q3);
  }

  int w = tid >> 6, l = tid & 63;
  int lr = l & 15, lg = l >> 4;
  // wave w covers WKVT cols [w*32, w*32+32): w<4 -> K heads 2w,2w+1; w>=4 -> V
  const unsigned short* wb = WKVT + (size_t)(w * 32 + lr) * 128 + lg * 8;
  bf16x8 Bcur0 = *(const bf16x8*)(wb);
  bf16x8 Bcur1 = *(const bf16x8*)(wb + 16 * 128);
  f32x4 acc[4][2] = {};
  __syncthreads();

#pragma unroll
  for (int ks = 0; ks < 4; ++ks) {
    bf16x8 Bn0, Bn1;
    if (ks < 3) {
      Bn0 = *(const bf16x8*)(wb + (ks + 1) * 32);
      Bn1 = *(const bf16x8*)(wb + 16 * 128 + (ks + 1) * 32);
    }
#pragma unroll
    for (int mi = 0; mi < 4; ++mi) {
      int row = mi * 16 + lr;
      int ku = ks * 32 + lg * 8;
      bf16x8 a = *(const bf16x8*)(As + row * 128 + (ku ^ ((row & 7) << 3)));
      acc[mi][0] = __builtin_amdgcn_mfma_f32_16x16x32_bf16(a, Bcur0, acc[mi][0], 0, 0, 0);
      acc[mi][1] = __builtin_amdgcn_mfma_f32_16x16x32_bf16(a, Bcur1, acc[mi][1], 0, 0, 0);
    }
    if (ks < 3) { Bcur0 = Bn0; Bcur1 = Bn1; }
  }
  __syncthreads();  // all As reads done -> VtF region free

  // run detection over Sjn (wave 0; 64-bit ballot)
  if (tid < 64) {
    int flag = (tid == 0) || (Sjn[tid] != Sjn[tid - 1]);
    unsigned long long mask = __ballot(flag);
    int nr = __popcll(mask);
    if (flag) {
      int ri = __popcll(mask & ((1ull << tid) - 1ull));
      runStart[ri] = tid;
      runNode[ri] = Sjn[tid];
    }
    if (tid == 0) {
      nrunsS = nr;
      runStart[nr] = 64;
    }
  }

  // C layout: col = lane&15, row = (lane>>4)*4 + reg
  if (w < 4) {  // K waves: ex = exp(score) for heads 2w, 2w+1
    float bk0 = bK[w * 32 + lr], bk1 = bK[w * 32 + 16 + lr];
#pragma unroll
    for (int mi = 0; mi < 4; ++mi)
#pragma unroll
      for (int r = 0; r < 4; ++r) {
        int erow = mi * 16 + lg * 4 + r;
        int jn = Sjn[erow];
        const float* qrow = Q + (size_t)jn * D + w * 32;
        float q0 = qrow[lr], q1 = qrow[16 + lr];
        float t0 = (acc[mi][0][r] + bk0) * q0;
        float t1 = (acc[mi][1][r] + bk1) * q1;
        t0 += __shfl_xor(t0, 1); t1 += __shfl_xor(t1, 1);
        t0 += __shfl_xor(t0, 2); t1 += __shfl_xor(t1, 2);
        t0 += __shfl_xor(t0, 4); t1 += __shfl_xor(t1, 4);
        t0 += __shfl_xor(t0, 8); t1 += __shfl_xor(t1, 8);
        if (lr == 0) {
          Sex[erow][w * 2] = __expf(t0 * 0.25f);
          Sex[erow][w * 2 + 1] = __expf(t1 * 0.25f);
        }
      }
  } else {  // V waves: (V+bias)*phi -> f32 LDS (columns c0, c0+16)
    float bv0 = bV[(w - 4) * 32 + lr], bv1 = bV[(w - 4) * 32 + 16 + lr];
    int c0 = (w - 4) * 32 + lr;
#pragma unroll
    for (int mi = 0; mi < 4; ++mi)
#pragma unroll
      for (int r = 0; r < 4; ++r) {
        int row = mi * 16 + lg * 4 + r;
        float ph = Sphi[row];
        VtF[row][c0] = (acc[mi][0][r] + bv0) * ph;
        VtF[row][c0 + 16] = (acc[mi][1][r] + bv1) * ph;
      }
  }
  __syncthreads();

  // segmented reduction: 4 runs x 128 cols in parallel
  int nr = nrunsS;
  int col = tid & 127;
  int h = col >> 4;
  for (int ri = tid >> 7; ri < nr; ri += 4) {
    int r0 = runStart[ri], r1 = runStart[ri + 1];
    float s = 0.f;
    for (int r = r0; r < r1; ++r) s += VtF[r][col] * Sex[r][h];
    atomicAdd(&Pnum[(size_t)runNode[ri] * D + col], s);
  }
  if (tid < nr * NH) {
    int ri = tid >> 3, hh = tid & 7;
    int r0 = runStart[ri], r1 = runStart[ri + 1];
    float s = 0.f;
    for (int r = r0; r < r1; ++r) s += Sex[r][hh];
    atomicAdd(&Pden[(size_t)runNode[ri] * NH + hh], s);
  }
}

extern "C" void kernel_launch(void* const* d_in, const int* in_sizes, int n_in,
                              void* d_out, int out_size, void* d_ws, size_t ws_size,
                              hipStream_t stream) {
  const float* x     = (const float*)d_in[0];
  const int*   eidx  = (const int*)d_in[1];
  const int*   jidx  = eidx + NE;
  const float* eattr = (const float*)d_in[2];
  const float* elen  = (const float*)d_in[3];
  const float* W_Q   = (const float*)d_in[4];
  const float* b_Q   = (const float*)d_in[5];
  const float* W_K   = (const float*)d_in[6];
  const float* b_K   = (const float*)d_in[7];
  const float* W_V   = (const float*)d_in[8];
  const float* b_V   = (const float*)d_in[9];
  const float* W_O   = (const float*)d_in[10];
  const float* b_O   = (const float*)d_in[11];
  float* out = (float*)d_out;

  char* ws = (char*)d_ws;
  float* Q     = (float*)ws;             ws += (size_t)NN * D * 4;
  float* Pnum  = (float*)ws;             ws += (size_t)NN * D * 4;
  float* Pden  = (float*)ws;             ws += (size_t)NN * NH * 4;  // contiguous w/ Pnum
  int*   cnt   = (int*)ws;               ws += (size_t)NN * 4;
  int*   offs  = (int*)ws;               ws += (size_t)(NN + 1) * 4;
  int*   cursor= (int*)ws;               ws += (size_t)NN * 4;
  int*   elist = (int*)ws;               ws += (size_t)NE * 4;
  // WKVT (64KB) aliases cursor (200KB): cursor is dead after scatter_k.
  unsigned short* WKVT = (unsigned short*)cursor;

  hipMemsetAsync(cnt, 0, (size_t)NN * 4, stream);
  hipMemsetAsync(Pnum, 0, (size_t)NN * (D + NH) * 4, stream);

  hist_k<<<NE / 256, 256, 0, stream>>>(jidx, cnt);
  scan_k<<<1, 1024, 0, stream>>>(cnt, offs, cursor);
  scatter_k<<<NE / 256, 256, 0, stream>>>(jidx, cursor, elist);
  wprep_k<<<256, 128, 0, stream>>>(W_K, W_V, WKVT);

  gemm_bias_k<<<(NN + 63) / 64, 256, 0, stream>>>(x, W_Q, b_Q, Q, NN);
  kvagg_k<<<NE / 64, 512, 0, stream>>>(eattr, WKVT, b_K, b_V, Q, jidx, elen,
                                       elist, Pnum, Pden);
  gemm_norm_bias_k<<<(NN + 63) / 64, 256, 0, stream>>>(Pnum, Pden, W_O, b_O, out, NN);
}